// Round 10
// baseline (393.047 us; speedup 1.0000x reference)
//
#include <hip/hip_runtime.h>
#include <hip/hip_bf16.h>

typedef __bf16 bf16x8 __attribute__((ext_vector_type(8)));
typedef float f32x4 __attribute__((ext_vector_type(4)));
typedef unsigned short ushort_t;

#define NPOS 512
#define CIN  5
#define CO   128

static __device__ __forceinline__ unsigned short f2bf(float f){
  union { __hip_bfloat16 h; unsigned short u; } cv;
  cv.h = __float2bfloat16(f);
  return cv.u;
}

// packed f32->bf16x2 (v_cvt_pk_bf16_f32 on gfx950) — RNE, 1 op per 2 values
static __device__ __forceinline__ unsigned cvtpk_u32(float a, float b){
  union { __hip_bfloat162 h2; unsigned u; } cv;
  cv.h2 = __float22bfloat162_rn(make_float2(a, b));
  return cv.u;
}

// packed u16 min/max (VOP3P) — one op handles two independent sort rows
static __device__ __forceinline__ unsigned pk_min_u16(unsigned a, unsigned b){
  unsigned d; asm("v_pk_min_u16 %0, %1, %2" : "=v"(d) : "v"(a), "v"(b)); return d;
}
static __device__ __forceinline__ unsigned pk_max_u16(unsigned a, unsigned b){
  unsigned d; asm("v_pk_max_u16 %0, %1, %2" : "=v"(d) : "v"(a), "v"(b)); return d;
}
// packed i16 max — relu on 2 packed bf16 (sign-correct; -0.0 -> +0.0)
static __device__ __forceinline__ unsigned pk_max_i16(unsigned a, unsigned b){
  unsigned d; asm("v_pk_max_i16 %0, %1, %2" : "=v"(d) : "v"(a), "v"(b)); return d;
}

// DPP cross-lane fetch (VALU pipe, no DS): 0xB1=xor1, 0x4E=xor2, 0x128=xor8
template<int CTRL>
static __device__ __forceinline__ unsigned mov_dpp_u32(unsigned v){
  return (unsigned)__builtin_amdgcn_mov_dpp((int)v, CTRL, 0xf, 0xf, true);
}
template<int CTRL>
static __device__ __forceinline__ float fadd_dpp(float s){
  union {float f; int i;} u; u.f = s;
  union {int i; float f;} q; q.i = __builtin_amdgcn_mov_dpp(u.i, CTRL, 0xf, 0xf, true);
  return s + q.f;
}

// ---------------- weight fp32 -> bf16 prep (+ fspool weight table) ----------------
// o = [w2b 65536 | w3b 65536 | w4b 32768 | w1b 8192 (256 d x 32 k, k>=5 zero)]
// Wt[c][i] (f32, 128x512) = piecewise-linear pool weight at descending rank 511-i
__global__ void k_prep(const float* __restrict__ w1, const float* __restrict__ w2,
                       const float* __restrict__ w3, const float* __restrict__ w4,
                       const float* __restrict__ pw,
                       ushort_t* __restrict__ o, float* __restrict__ Wt){
  int i = blockIdx.x*256 + threadIdx.x;   // grid covers 237568 exactly
  if (i < 65536)        o[i] = f2bf(w2[i]);
  else if (i < 131072)  o[i] = f2bf(w3[i-65536]);
  else if (i < 163840)  o[i] = f2bf(w4[i-131072]);
  else if (i < 172032){
    int j = i - 163840;                   // 0..8191
    int d = j >> 5, k = j & 31;
    o[i] = (k < CIN) ? f2bf(w1[d*CIN + k]) : (ushort_t)0;
  } else {
    int j = i - 172032;                   // 0..65535
    int c = j >> 9, ii = j & 511;
    int rk = 511 - ii;
    float pos = (float)rk * (20.0f/511.0f);
    int idx = (int)pos; if (idx > 20) idx = 20;
    float frac = pos - (float)idx;
    int i2 = (idx+1 > 20) ? 20 : idx+1;
    float wl = pw[c*21 + idx], wr = pw[c*21 + i2];
    Wt[c*512 + ii] = wl + frac*(wr - wl);
  }
}

// ---------------- fused conv1..conv4 (all-MFMA, 2-tile W reuse) ----------------
// Block owns (batch b, 128-n pair of tiles). Two in-place 32 KB Act buffers,
// fragment-major chunks: chunk(n,c) = (n>>4)*512 + (c>>5)*64 + ((c>>3)&3)*16 + (n&15),
// j-slot = c&7. Act-read (nb,ks): chunk = nb*512 + ks*64 + lane (lane-seq b128).
//
// R10: cross-layer W prefetch moved INSIDE the mfma ks-loop (ks=6/7 load the
// NEXT layer's ks0/ks1 into just-freed slots). The old placement issued the
// loads right before __syncthreads, whose vmcnt(0) drain exposed full L2
// latency 7x/block. Slot index = (ks+SOFF)%3, SOFF_next = (SOFF+NKS)%3:
//   L1 SOFF=0 (W2 head pre-staged in slots 1,2) -> L2 SOFF=1 -> L3 SOFF=0
//   -> L4 SOFF=2.  All preload targets verified consumed-before-write.

template<int NSD, int KSTR>
static __device__ __forceinline__ void preload_w(bf16x8 (&wr)[3][4],
    const ushort_t* __restrict__ Wb, int slot, int ks, int wave, int lane){
  const int m = lane & 15, quad = lane >> 4;
  const int d0 = wave * (NSD*16);
  #pragma unroll
  for (int sd=0; sd<NSD; sd++)
    wr[slot][sd] = *(const bf16x8*)(Wb + (d0 + sd*16 + m)*KSTR + ks*32 + quad*8);
}

// layers 1-3: W as A-operand, Act as B-operand. acc[nb][db]:
//   n = nb*16 + (lane&15), d = wave*64 + db*16 + quad*4 + rg
// NSDN>0: at ks=6/7 preload next layer's ks0/ks1 (NSDN = next layer's NSD).
template<int NKS, int SOFF, int NSDN>
static __device__ __forceinline__ void mfma_WA(bf16x8 (&wr)[3][4],
    const ushort_t* __restrict__ Wb, const ushort_t* __restrict__ Wbn,
    const ushort_t* __restrict__ A0, const ushort_t* __restrict__ A1,
    const float* __restrict__ bias,
    f32x4 (&c0)[4][4], f32x4 (&c1)[4][4], int wave, int lane){
  const int quad = lane >> 4;
  #pragma unroll
  for (int db=0; db<4; db++){
    float4 b4v = *(const float4*)(bias + wave*64 + db*16 + quad*4);
    f32x4 bvv = (f32x4){b4v.x, b4v.y, b4v.z, b4v.w};
    #pragma unroll
    for (int nb=0; nb<4; nb++){ c0[nb][db] = bvv; c1[nb][db] = bvv; }
  }
  #pragma unroll
  for (int ks=0; ks<NKS; ks++){
    if (ks+2 < NKS) preload_w<4,256>(wr, Wb, (ks+2+SOFF)%3, ks+2, wave, lane);
    else if constexpr (NSDN > 0){
      if (NKS == 8 && ks >= 6)
        preload_w<NSDN,256>(wr, Wbn, (ks+2+SOFF)%3, ks-6, wave, lane);
    }
    bf16x8 a0[4], a1[4];
    #pragma unroll
    for (int nb=0; nb<4; nb++){
      a0[nb] = *(const bf16x8*)(A0 + ((nb*512 + ks*64 + lane) << 3));
      a1[nb] = *(const bf16x8*)(A1 + ((nb*512 + ks*64 + lane) << 3));
    }
    #pragma unroll
    for (int db=0; db<4; db++){
      #pragma unroll
      for (int nb=0; nb<4; nb++){
        c0[nb][db] = __builtin_amdgcn_mfma_f32_16x16x32_bf16(wr[(ks+SOFF)%3][db], a0[nb], c0[nb][db], 0,0,0);
        c1[nb][db] = __builtin_amdgcn_mfma_f32_16x16x32_bf16(wr[(ks+SOFF)%3][db], a1[nb], c1[nb][db], 0,0,0);
      }
    }
  }
}

// layer 4: Act as A-operand (old orientation). acc[sn][sd]:
//   n = sn*16 + quad*4 + rg, d = wave*32 + sd*16 + (lane&15)
template<int SOFF>
static __device__ __forceinline__ void mfma_L4(bf16x8 (&wr)[3][4],
    const ushort_t* __restrict__ Wb,
    const ushort_t* __restrict__ A0, const ushort_t* __restrict__ A1,
    const float* __restrict__ bias,
    f32x4 (&c0)[4][4], f32x4 (&c1)[4][4], int wave, int lane){
  const int m = lane & 15;
  #pragma unroll
  for (int sd=0; sd<2; sd++){
    float bv = bias[wave*32 + sd*16 + m];
    f32x4 bvv = (f32x4){bv,bv,bv,bv};
    #pragma unroll
    for (int sn=0; sn<4; sn++){ c0[sn][sd] = bvv; c1[sn][sd] = bvv; }
  }
  #pragma unroll
  for (int ks=0; ks<8; ks++){
    if (ks+2 < 8) preload_w<2,256>(wr, Wb, (ks+2+SOFF)%3, ks+2, wave, lane);
    bf16x8 a0[4], a1[4];
    #pragma unroll
    for (int sn=0; sn<4; sn++){
      a0[sn] = *(const bf16x8*)(A0 + ((sn*512 + ks*64 + lane) << 3));
      a1[sn] = *(const bf16x8*)(A1 + ((sn*512 + ks*64 + lane) << 3));
    }
    #pragma unroll
    for (int sd=0; sd<2; sd++){
      #pragma unroll
      for (int sn=0; sn<4; sn++){
        c0[sn][sd] = __builtin_amdgcn_mfma_f32_16x16x32_bf16(a0[sn], wr[(ks+SOFF)%3][sd], c0[sn][sd], 0,0,0);
        c1[sn][sd] = __builtin_amdgcn_mfma_f32_16x16x32_bf16(a1[sn], wr[(ks+SOFF)%3][sd], c1[sn][sd], 0,0,0);
      }
    }
  }
}

// layers 1-3 epilogue: +relu, ONE b64 write per acc tile (4 consecutive c)
static __device__ __forceinline__ void epilogue_relu(const f32x4 (&c)[4][4],
    ushort_t* __restrict__ dst, int wave, int lane){
  const int m = lane & 15, quad = lane >> 4;
  #pragma unroll
  for (int db=0; db<4; db++){
    int cb    = wave*64 + db*16 + quad*4;
    int colpt = (cb>>5)*64 + ((cb>>3)&3)*16;     // chunk col part
    int half  = (quad & 1) ? 4 : 0;              // 8B half within 16B chunk
    #pragma unroll
    for (int nb=0; nb<4; nb++){
      unsigned u01 = pk_max_i16(cvtpk_u32(c[nb][db][0], c[nb][db][1]), 0u);
      unsigned u23 = pk_max_i16(cvtpk_u32(c[nb][db][2], c[nb][db][3]), 0u);
      int chunk = nb*512 + colpt + m;
      *(uint2*)&dst[(chunk << 3) + half] = make_uint2(u01, u23);
    }
  }
}

__global__ __launch_bounds__(256,2) void k_fused(
  const float* __restrict__ x, const float* __restrict__ mask,
  const ushort_t* __restrict__ w1b, const float* __restrict__ b1,
  const ushort_t* __restrict__ w2b, const float* __restrict__ b2,
  const ushort_t* __restrict__ w3b, const float* __restrict__ b3,
  const ushort_t* __restrict__ w4b, const float* __restrict__ b4,
  ushort_t* __restrict__ h4)
{
  __shared__ __align__(16) ushort_t Act0[64*256];   // 32 KB each, in-place
  __shared__ __align__(16) ushort_t Act1[64*256];
  const int t    = threadIdx.x;
  const int bid  = blockIdx.x;
  const int b    = bid >> 2;
  const int n0   = (bid & 3) << 7;       // tiles at n0 and n0+64
  const int wave = t >> 6, lane = t & 63;

  bf16x8 wr[3][4];
  f32x4  c0[4][4], c1[4][4];

  // Build layer-1 fragments (ks=0 chunks) straight from global x, both tiles.
  {
    const int sn = t >> 6, col = (t >> 4) & 3, n16 = t & 15;
    uint4 u0 = make_uint4(0u,0u,0u,0u), u1 = u0;
    if (col == 0){
      const float* xp = x + (size_t)b*CIN*NPOS + n0 + sn*16 + n16;
      u0.x = cvtpk_u32(xp[0],      xp[NPOS]);
      u0.y = cvtpk_u32(xp[2*NPOS], xp[3*NPOS]);
      u0.z = cvtpk_u32(xp[4*NPOS], 0.f);
      const float* xq = xp + 64;
      u1.x = cvtpk_u32(xq[0],      xq[NPOS]);
      u1.y = cvtpk_u32(xq[2*NPOS], xq[3*NPOS]);
      u1.z = cvtpk_u32(xq[4*NPOS], 0.f);
    }
    *(uint4*)&Act0[(sn*512 + col*16 + n16) << 3] = u0;
    *(uint4*)&Act1[(sn*512 + col*16 + n16) << 3] = u1;
  }
  preload_w<4,32>(wr, w1b, 0, 0, wave, lane);     // W1 (K=32 padded) -> slot 0
  preload_w<4,256>(wr, w2b, 1, 0, wave, lane);    // W2 ks0 -> slot 1 (L2 SOFF=1)
  preload_w<4,256>(wr, w2b, 2, 1, wave, lane);    // W2 ks1 -> slot 2
  __syncthreads();                                // (1) x-frags ready

  mfma_WA<1,0,0>(wr, w1b, nullptr, Act0, Act1, b1, c0, c1, wave, lane);   // L1
  __syncthreads();                                // (2) x-frag reads done
  epilogue_relu(c0, Act0, wave, lane);
  epilogue_relu(c1, Act1, wave, lane);
  __syncthreads();                                // (3) Act = h1

  mfma_WA<8,1,4>(wr, w2b, w3b, Act0, Act1, b2, c0, c1, wave, lane);       // L2
  __syncthreads();                                // (4) h1 reads done
  epilogue_relu(c0, Act0, wave, lane);
  epilogue_relu(c1, Act1, wave, lane);
  __syncthreads();                                // (5) Act = h2

  mfma_WA<8,0,2>(wr, w3b, w4b, Act0, Act1, b3, c0, c1, wave, lane);       // L3
  __syncthreads();                                // (6) h2 reads done
  epilogue_relu(c0, Act0, wave, lane);
  epilogue_relu(c1, Act1, wave, lane);
  __syncthreads();                                // (7) Act = h3

  mfma_L4<2>(wr, w4b, Act0, Act1, b4, c0, c1, wave, lane);                // L4
  {
    const int m = lane & 15, quad = lane >> 4;
    const float* mk = mask + (size_t)b*NPOS + n0;
    #pragma unroll
    for (int sd=0;sd<2;sd++){
      const int d = wave*32 + sd*16 + m;
      ushort_t* rowp = h4 + ((size_t)b*CO + d)*NPOS + n0;
      #pragma unroll
      for (int sn=0;sn<4;sn++){
        float4 mr0 = *(const float4*)(mk + sn*16 + quad*4);
        float4 mr1 = *(const float4*)(mk + 64 + sn*16 + quad*4);
        unsigned q0 = cvtpk_u32(c0[sn][sd][0] * (1.0f/512.0f) * mr0.x,
                                c0[sn][sd][1] * (1.0f/512.0f) * mr0.y);
        unsigned q1 = cvtpk_u32(c0[sn][sd][2] * (1.0f/512.0f) * mr0.z,
                                c0[sn][sd][3] * (1.0f/512.0f) * mr0.w);
        *(uint2*)(rowp + sn*16 + quad*4) = make_uint2(q0, q1);
        unsigned p0 = cvtpk_u32(c1[sn][sd][0] * (1.0f/512.0f) * mr1.x,
                                c1[sn][sd][1] * (1.0f/512.0f) * mr1.y);
        unsigned p1 = cvtpk_u32(c1[sn][sd][2] * (1.0f/512.0f) * mr1.z,
                                c1[sn][sd][3] * (1.0f/512.0f) * mr1.w);
        *(uint2*)(rowp + 64 + sn*16 + quad*4) = make_uint2(p0, p1);
      }
    }
  }
}

// ---------------- sort + pool (+ size feature fold) ----------------
// Packed bitonic, TWO rows per wave (row0 low u16 / row1 high u16 of 8 regs).
// xor 1,2,8 via DPP (VALU pipe); 4,16,32 via __shfl_xor. Direction-flip trick
// makes every CE fixed-ascending. R10: Wt weight loads hoisted ABOVE the sort
// so their L2 latency hides under ~2200 cyc of bitonic VALU (was tail-exposed).

static __device__ __forceinline__ void ce_up(unsigned &a, unsigned &b){
  unsigned mn = pk_min_u16(a,b), mx = pk_max_u16(a,b); a = mn; b = mx;
}
static __device__ __forceinline__ void ce_dn(unsigned &a, unsigned &b){
  unsigned mn = pk_min_u16(a,b), mx = pk_max_u16(a,b); a = mx; b = mn;
}
static __device__ __forceinline__ void clean8(unsigned (&v)[8]){   // j=4,2,1 ascending
  ce_up(v[0],v[4]); ce_up(v[1],v[5]); ce_up(v[2],v[6]); ce_up(v[3],v[7]);
  ce_up(v[0],v[2]); ce_up(v[1],v[3]); ce_up(v[4],v[6]); ce_up(v[5],v[7]);
  ce_up(v[0],v[1]); ce_up(v[2],v[3]); ce_up(v[4],v[5]); ce_up(v[6],v[7]);
}
static __device__ __forceinline__ void flip8(unsigned (&v)[8], unsigned f){
  #pragma unroll
  for (int i=0;i<8;i++) v[i] ^= f;
}
template<int CTRL>
static __device__ __forceinline__ void xr_dpp(unsigned (&v)[8], bool low){
  #pragma unroll
  for (int i=0;i<8;i++){
    unsigned p = mov_dpp_u32<CTRL>(v[i]);
    unsigned mn = pk_min_u16(v[i], p), mx = pk_max_u16(v[i], p);
    v[i] = low ? mn : mx;
  }
}
static __device__ __forceinline__ void xr_shfl(unsigned (&v)[8], int lm, bool low){
  #pragma unroll
  for (int i=0;i<8;i++){
    unsigned p = (unsigned)__shfl_xor((int)v[i], lm);
    unsigned mn = pk_min_u16(v[i], p), mx = pk_max_u16(v[i], p);
    v[i] = low ? mn : mx;
  }
}

__global__ void k_pool(const ushort_t* __restrict__ h4, const float* __restrict__ Wt,
                       const float* __restrict__ mask, float* __restrict__ out)
{
  const int lane = threadIdx.x & 63;
  const int wave = threadIdx.x >> 6;
  const size_t r0 = (size_t)blockIdx.x*8 + wave*2;   // rows r0, r0+1
  const int b0 = (int)(r0 >> 7), c0 = (int)(r0 & 127);
  const int b1_ = (int)((r0+1) >> 7), c1 = (int)((r0+1) & 127);

  uint4 ra = *(const uint4*)(h4 + r0*NPOS     + lane*8);
  uint4 rb = *(const uint4*)(h4 + (r0+1)*NPOS + lane*8);

  // Wt loads issued NOW — latency hidden under the sort below
  float w0[8], w1a[8];
  *(float4*)&w0[0]  = *(const float4*)(Wt + c0*512 + lane*8);
  *(float4*)&w0[4]  = *(const float4*)(Wt + c0*512 + lane*8 + 4);
  *(float4*)&w1a[0] = *(const float4*)(Wt + c1*512 + lane*8);
  *(float4*)&w1a[4] = *(const float4*)(Wt + c1*512 + lane*8 + 4);

  unsigned v[8];
  v[0] = (ra.x & 0xFFFFu) | (rb.x << 16);
  v[1] = (ra.x >> 16)     | (rb.x & 0xFFFF0000u);
  v[2] = (ra.y & 0xFFFFu) | (rb.y << 16);
  v[3] = (ra.y >> 16)     | (rb.y & 0xFFFF0000u);
  v[4] = (ra.z & 0xFFFFu) | (rb.z << 16);
  v[5] = (ra.z >> 16)     | (rb.z & 0xFFFF0000u);
  v[6] = (ra.w & 0xFFFFu) | (rb.w << 16);
  v[7] = (ra.w >> 16)     | (rb.w & 0xFFFF0000u);

  // bf16 -> sortable u16 key (both halves at once)
  #pragma unroll
  for (int i=0;i<8;i++){
    unsigned sb = (v[i] >> 15) & 0x00010001u;
    v[i] = v[i] ^ 0x80008000u ^ (sb * 0x7FFFu);
  }

  const bool lo1  = (lane & 1)  == 0;
  const bool lo2  = (lane & 2)  == 0;
  const bool lo4  = (lane & 4)  == 0;
  const bool lo8  = (lane & 8)  == 0;
  const bool lo16 = (lane & 16) == 0;
  const bool lo32 = (lane & 32) == 0;

  const unsigned F8   = (lane & 1)  ? 0xFFFFFFFFu : 0u;
  const unsigned F16  = (lane & 2)  ? 0xFFFFFFFFu : 0u;
  const unsigned F32  = (lane & 4)  ? 0xFFFFFFFFu : 0u;
  const unsigned F64  = (lane & 8)  ? 0xFFFFFFFFu : 0u;
  const unsigned F128 = (lane & 16) ? 0xFFFFFFFFu : 0u;
  const unsigned F256 = (lane & 32) ? 0xFFFFFFFFu : 0u;

  // k=2, k=4 presort (fixed directions)
  ce_up(v[0],v[1]); ce_dn(v[2],v[3]); ce_up(v[4],v[5]); ce_dn(v[6],v[7]);
  ce_up(v[0],v[2]); ce_up(v[1],v[3]); ce_dn(v[4],v[6]); ce_dn(v[5],v[7]);
  ce_up(v[0],v[1]); ce_up(v[2],v[3]); ce_dn(v[4],v[5]); ce_dn(v[6],v[7]);

  flip8(v, F8);                                   // k=8 (in-lane only)
  clean8(v);
  flip8(v, F8 ^ F16);                             // k=16
  xr_dpp<0xB1>(v, lo1);
  clean8(v);
  flip8(v, F16 ^ F32);                            // k=32
  xr_dpp<0x4E>(v, lo2); xr_dpp<0xB1>(v, lo1);
  clean8(v);
  flip8(v, F32 ^ F64);                            // k=64
  xr_shfl(v, 4, lo4); xr_dpp<0x4E>(v, lo2); xr_dpp<0xB1>(v, lo1);
  clean8(v);
  flip8(v, F64 ^ F128);                           // k=128
  xr_dpp<0x128>(v, lo8); xr_shfl(v, 4, lo4); xr_dpp<0x4E>(v, lo2); xr_dpp<0xB1>(v, lo1);
  clean8(v);
  flip8(v, F128 ^ F256);                          // k=256
  xr_shfl(v, 16, lo16); xr_dpp<0x128>(v, lo8); xr_shfl(v, 4, lo4);
  xr_dpp<0x4E>(v, lo2); xr_dpp<0xB1>(v, lo1);
  clean8(v);
  flip8(v, F256);                                 // k=512 runs unflipped
  xr_shfl(v, 32, lo32); xr_shfl(v, 16, lo16); xr_dpp<0x128>(v, lo8);
  xr_shfl(v, 4, lo4); xr_dpp<0x4E>(v, lo2); xr_dpp<0xB1>(v, lo1);
  clean8(v);

  // key -> bf16 bits (both halves)
  #pragma unroll
  for (int i=0;i<8;i++){
    unsigned sb = ((~v[i]) >> 15) & 0x00010001u;
    v[i] = v[i] ^ 0x80008000u ^ (sb * 0x7FFFu);
  }

  float s0 = 0.f, s1 = 0.f;
  #pragma unroll
  for (int i=0;i<8;i++){
    union {unsigned u; float f;} lo, hi;
    lo.u = v[i] << 16;
    hi.u = v[i] & 0xFFFF0000u;
    s0 = fmaf(lo.f, w0[i],  s0);
    s1 = fmaf(hi.f, w1a[i], s1);
  }
  s0 = fadd_dpp<0xB1>(s0);  s1 = fadd_dpp<0xB1>(s1);
  s0 = fadd_dpp<0x4E>(s0);  s1 = fadd_dpp<0x4E>(s1);
  s0 = fadd_dpp<0x128>(s0); s1 = fadd_dpp<0x128>(s1);
  s0 += __shfl_xor(s0, 4);  s1 += __shfl_xor(s1, 4);
  s0 += __shfl_xor(s0, 16); s1 += __shfl_xor(s1, 16);
  s0 += __shfl_xor(s0, 32); s1 += __shfl_xor(s1, 32);

  if (lane == 0){
    out[b0*129 + c0]  = s0;
    out[b1_*129 + c1] = s1;
  }

  // folded size feature: blocks 0..1023, wave 0 compute out[b,128]
  if (blockIdx.x < 1024 && wave == 0){
    const int b = blockIdx.x;
    float s = 0.f;
    #pragma unroll
    for (int i=0;i<2;i++){
      float4 mv = *(const float4*)(mask + (size_t)b*NPOS + lane*8 + i*4);
      s += mv.x + mv.y + mv.z + mv.w;
    }
    s = fadd_dpp<0xB1>(s); s = fadd_dpp<0x4E>(s); s = fadd_dpp<0x128>(s);
    s += __shfl_xor(s, 4); s += __shfl_xor(s, 16); s += __shfl_xor(s, 32);
    if (lane == 0) out[b*129 + 128] = s * (1.0f/128.0f);  // mean*4 = sum/512*4
  }
}

extern "C" void kernel_launch(void* const* d_in, const int* in_sizes, int n_in,
                              void* d_out, int out_size, void* d_ws, size_t ws_size,
                              hipStream_t stream){
  const float* x    = (const float*)d_in[0];
  const float* mask = (const float*)d_in[1];
  const float* w1   = (const float*)d_in[2];
  const float* b1   = (const float*)d_in[3];
  const float* w2   = (const float*)d_in[4];
  const float* b2   = (const float*)d_in[5];
  const float* w3   = (const float*)d_in[6];
  const float* b3   = (const float*)d_in[7];
  const float* w4   = (const float*)d_in[8];
  const float* b4   = (const float*)d_in[9];
  const float* pw   = (const float*)d_in[10];
  float* out = (float*)d_out;

  // ws: h4 bf16 (1024*128*512 = 128MB) | w2b | w3b | w4b | w1b | Wt (f32 128x512)
  ushort_t* h4  = (ushort_t*)d_ws;
  ushort_t* w2b = h4 + (size_t)1024*CO*NPOS;
  ushort_t* w3b = w2b + 65536;
  ushort_t* w4b = w3b + 65536;
  ushort_t* w1b = w4b + 32768;
  float*    Wt  = (float*)(w1b + 8192);

  k_prep <<<928,   256, 0, stream>>>(w1, w2, w3, w4, pw, w2b, Wt);
  k_fused<<<4096,  256, 0, stream>>>(x, mask, w1b, b1, w2b, b2, w3b, b3, w4b, b4, h4);
  k_pool <<<16384, 256, 0, stream>>>(h4, Wt, mask, out);
}

// Round 11
// 385.171 us; speedup vs baseline: 1.0204x; 1.0204x over previous
//
#include <hip/hip_runtime.h>
#include <hip/hip_bf16.h>

typedef __bf16 bf16x8 __attribute__((ext_vector_type(8)));
typedef float f32x4 __attribute__((ext_vector_type(4)));
typedef unsigned short ushort_t;

#define NPOS 512
#define CIN  5
#define CO   128

static __device__ __forceinline__ unsigned short f2bf(float f){
  union { __hip_bfloat16 h; unsigned short u; } cv;
  cv.h = __float2bfloat16(f);
  return cv.u;
}

// packed f32->bf16x2 (v_cvt_pk_bf16_f32 on gfx950) — RNE, 1 op per 2 values
static __device__ __forceinline__ unsigned cvtpk_u32(float a, float b){
  union { __hip_bfloat162 h2; unsigned u; } cv;
  cv.h2 = __float22bfloat162_rn(make_float2(a, b));
  return cv.u;
}

// packed u16 min/max (VOP3P) — one op handles two independent sort rows
static __device__ __forceinline__ unsigned pk_min_u16(unsigned a, unsigned b){
  unsigned d; asm("v_pk_min_u16 %0, %1, %2" : "=v"(d) : "v"(a), "v"(b)); return d;
}
static __device__ __forceinline__ unsigned pk_max_u16(unsigned a, unsigned b){
  unsigned d; asm("v_pk_max_u16 %0, %1, %2" : "=v"(d) : "v"(a), "v"(b)); return d;
}
// packed i16 max — relu on 2 packed bf16 (sign-correct; -0.0 -> +0.0)
static __device__ __forceinline__ unsigned pk_max_i16(unsigned a, unsigned b){
  unsigned d; asm("v_pk_max_i16 %0, %1, %2" : "=v"(d) : "v"(a), "v"(b)); return d;
}

// DPP cross-lane fetch (VALU pipe, no DS): 0xB1=xor1, 0x4E=xor2, 0x128=xor8
template<int CTRL>
static __device__ __forceinline__ unsigned mov_dpp_u32(unsigned v){
  return (unsigned)__builtin_amdgcn_mov_dpp((int)v, CTRL, 0xf, 0xf, true);
}
template<int CTRL>
static __device__ __forceinline__ float fadd_dpp(float s){
  union {float f; int i;} u; u.f = s;
  union {int i; float f;} q; q.i = __builtin_amdgcn_mov_dpp(u.i, CTRL, 0xf, 0xf, true);
  return s + q.f;
}

// ---------------- weight fp32 -> bf16 prep (+ fspool weight table) ----------------
// o = [w2b 65536 | w3b 65536 | w4b 32768 | w1b 8192 (256 d x 32 k, k>=5 zero)]
// Wt[c][i] (f32, 128x512) = piecewise-linear pool weight at descending rank 511-i
__global__ void k_prep(const float* __restrict__ w1, const float* __restrict__ w2,
                       const float* __restrict__ w3, const float* __restrict__ w4,
                       const float* __restrict__ pw,
                       ushort_t* __restrict__ o, float* __restrict__ Wt){
  int i = blockIdx.x*256 + threadIdx.x;   // grid covers 237568 exactly
  if (i < 65536)        o[i] = f2bf(w2[i]);
  else if (i < 131072)  o[i] = f2bf(w3[i-65536]);
  else if (i < 163840)  o[i] = f2bf(w4[i-131072]);
  else if (i < 172032){
    int j = i - 163840;                   // 0..8191
    int d = j >> 5, k = j & 31;
    o[i] = (k < CIN) ? f2bf(w1[d*CIN + k]) : (ushort_t)0;
  } else {
    int j = i - 172032;                   // 0..65535
    int c = j >> 9, ii = j & 511;
    int rk = 511 - ii;
    float pos = (float)rk * (20.0f/511.0f);
    int idx = (int)pos; if (idx > 20) idx = 20;
    float frac = pos - (float)idx;
    int i2 = (idx+1 > 20) ? 20 : idx+1;
    float wl = pw[c*21 + idx], wr = pw[c*21 + i2];
    Wt[c*512 + ii] = wl + frac*(wr - wl);
  }
}

// ---------------- fused conv1..conv4 (all-MFMA, 2-tile W reuse) ----------------
// Block owns (batch b, 128-n pair of tiles). Two in-place 32 KB Act buffers,
// fragment-major chunks: chunk(n,c) = (n>>4)*512 + (c>>5)*64 + ((c>>3)&3)*16 + (n&15),
// j-slot = c&7. Act-read (nb,ks): chunk = nb*512 + ks*64 + lane (lane-seq b128).
//
// R11 (post R10-spill revert): R9 structure, plus
//  (1) bias fed directly as C operand of ks=0 MFMAs (no 128-reg broadcast);
//  (2) next-layer W preloads issued AFTER the read-completion barrier, behind
//      the epilogue's VALU work (pre-barrier vmcnt(0) drain has nothing to wait
//      on; epilogue covers most of the W L2 latency). Same register budget as
//      R9 — R10's in-loop variant spilled (FETCH/WRITE +30%).

template<int NSD, int KSTR>
static __device__ __forceinline__ void preload_w(bf16x8 (&wr)[3][4],
    const ushort_t* __restrict__ Wb, int slot, int ks, int wave, int lane){
  const int m = lane & 15, quad = lane >> 4;
  const int d0 = wave * (NSD*16);
  #pragma unroll
  for (int sd=0; sd<NSD; sd++)
    wr[slot][sd] = *(const bf16x8*)(Wb + (d0 + sd*16 + m)*KSTR + ks*32 + quad*8);
}

// layers 1-3: W as A-operand, Act as B-operand. acc[nb][db]:
//   n = nb*16 + (lane&15), d = wave*64 + db*16 + quad*4 + rg
template<int NKS>
static __device__ __forceinline__ void mfma_WA(bf16x8 (&wr)[3][4],
    const ushort_t* __restrict__ Wb,
    const ushort_t* __restrict__ A0, const ushort_t* __restrict__ A1,
    const float* __restrict__ bias,
    f32x4 (&c0)[4][4], f32x4 (&c1)[4][4], int wave, int lane){
  const int quad = lane >> 4;
  f32x4 bvv[4];
  #pragma unroll
  for (int db=0; db<4; db++){
    float4 b4v = *(const float4*)(bias + wave*64 + db*16 + quad*4);
    bvv[db] = (f32x4){b4v.x, b4v.y, b4v.z, b4v.w};
  }
  #pragma unroll
  for (int ks=0; ks<NKS; ks++){
    if (ks+2 < NKS) preload_w<4,256>(wr, Wb, (ks+2)%3, ks+2, wave, lane);
    bf16x8 a0[4], a1[4];
    #pragma unroll
    for (int nb=0; nb<4; nb++){
      a0[nb] = *(const bf16x8*)(A0 + ((nb*512 + ks*64 + lane) << 3));
      a1[nb] = *(const bf16x8*)(A1 + ((nb*512 + ks*64 + lane) << 3));
    }
    #pragma unroll
    for (int db=0; db<4; db++){
      #pragma unroll
      for (int nb=0; nb<4; nb++){
        if (ks == 0){
          c0[nb][db] = __builtin_amdgcn_mfma_f32_16x16x32_bf16(wr[0][db], a0[nb], bvv[db], 0,0,0);
          c1[nb][db] = __builtin_amdgcn_mfma_f32_16x16x32_bf16(wr[0][db], a1[nb], bvv[db], 0,0,0);
        } else {
          c0[nb][db] = __builtin_amdgcn_mfma_f32_16x16x32_bf16(wr[ks%3][db], a0[nb], c0[nb][db], 0,0,0);
          c1[nb][db] = __builtin_amdgcn_mfma_f32_16x16x32_bf16(wr[ks%3][db], a1[nb], c1[nb][db], 0,0,0);
        }
      }
    }
  }
}

// layer 4: Act as A-operand (old orientation). acc[sn][sd]:
//   n = sn*16 + quad*4 + rg, d = wave*32 + sd*16 + (lane&15)
static __device__ __forceinline__ void mfma_L4(bf16x8 (&wr)[3][4],
    const ushort_t* __restrict__ Wb,
    const ushort_t* __restrict__ A0, const ushort_t* __restrict__ A1,
    const float* __restrict__ bias,
    f32x4 (&c0)[4][4], f32x4 (&c1)[4][4], int wave, int lane){
  const int m = lane & 15;
  f32x4 bvv[2];
  #pragma unroll
  for (int sd=0; sd<2; sd++){
    float bv = bias[wave*32 + sd*16 + m];
    bvv[sd] = (f32x4){bv,bv,bv,bv};
  }
  #pragma unroll
  for (int ks=0; ks<8; ks++){
    if (ks+2 < 8) preload_w<2,256>(wr, Wb, (ks+2)%3, ks+2, wave, lane);
    bf16x8 a0[4], a1[4];
    #pragma unroll
    for (int sn=0; sn<4; sn++){
      a0[sn] = *(const bf16x8*)(A0 + ((sn*512 + ks*64 + lane) << 3));
      a1[sn] = *(const bf16x8*)(A1 + ((sn*512 + ks*64 + lane) << 3));
    }
    #pragma unroll
    for (int sd=0; sd<2; sd++){
      #pragma unroll
      for (int sn=0; sn<4; sn++){
        if (ks == 0){
          c0[sn][sd] = __builtin_amdgcn_mfma_f32_16x16x32_bf16(a0[sn], wr[0][sd], bvv[sd], 0,0,0);
          c1[sn][sd] = __builtin_amdgcn_mfma_f32_16x16x32_bf16(a1[sn], wr[0][sd], bvv[sd], 0,0,0);
        } else {
          c0[sn][sd] = __builtin_amdgcn_mfma_f32_16x16x32_bf16(a0[sn], wr[ks%3][sd], c0[sn][sd], 0,0,0);
          c1[sn][sd] = __builtin_amdgcn_mfma_f32_16x16x32_bf16(a1[sn], wr[ks%3][sd], c1[sn][sd], 0,0,0);
        }
      }
    }
  }
}

// layers 1-3 epilogue: +relu, ONE b64 write per acc tile (4 consecutive c)
static __device__ __forceinline__ void epilogue_relu(const f32x4 (&c)[4][4],
    ushort_t* __restrict__ dst, int wave, int lane){
  const int m = lane & 15, quad = lane >> 4;
  #pragma unroll
  for (int db=0; db<4; db++){
    int cb    = wave*64 + db*16 + quad*4;
    int colpt = (cb>>5)*64 + ((cb>>3)&3)*16;     // chunk col part
    int half  = (quad & 1) ? 4 : 0;              // 8B half within 16B chunk
    #pragma unroll
    for (int nb=0; nb<4; nb++){
      unsigned u01 = pk_max_i16(cvtpk_u32(c[nb][db][0], c[nb][db][1]), 0u);
      unsigned u23 = pk_max_i16(cvtpk_u32(c[nb][db][2], c[nb][db][3]), 0u);
      int chunk = nb*512 + colpt + m;
      *(uint2*)&dst[(chunk << 3) + half] = make_uint2(u01, u23);
    }
  }
}

__global__ __launch_bounds__(256,2) void k_fused(
  const float* __restrict__ x, const float* __restrict__ mask,
  const ushort_t* __restrict__ w1b, const float* __restrict__ b1,
  const ushort_t* __restrict__ w2b, const float* __restrict__ b2,
  const ushort_t* __restrict__ w3b, const float* __restrict__ b3,
  const ushort_t* __restrict__ w4b, const float* __restrict__ b4,
  ushort_t* __restrict__ h4)
{
  __shared__ __align__(16) ushort_t Act0[64*256];   // 32 KB each, in-place
  __shared__ __align__(16) ushort_t Act1[64*256];
  const int t    = threadIdx.x;
  const int bid  = blockIdx.x;
  const int b    = bid >> 2;
  const int n0   = (bid & 3) << 7;       // tiles at n0 and n0+64
  const int wave = t >> 6, lane = t & 63;

  bf16x8 wr[3][4];
  f32x4  c0[4][4], c1[4][4];

  // Build layer-1 fragments (ks=0 chunks) straight from global x, both tiles.
  {
    const int sn = t >> 6, col = (t >> 4) & 3, n16 = t & 15;
    uint4 u0 = make_uint4(0u,0u,0u,0u), u1 = u0;
    if (col == 0){
      const float* xp = x + (size_t)b*CIN*NPOS + n0 + sn*16 + n16;
      u0.x = cvtpk_u32(xp[0],      xp[NPOS]);
      u0.y = cvtpk_u32(xp[2*NPOS], xp[3*NPOS]);
      u0.z = cvtpk_u32(xp[4*NPOS], 0.f);
      const float* xq = xp + 64;
      u1.x = cvtpk_u32(xq[0],      xq[NPOS]);
      u1.y = cvtpk_u32(xq[2*NPOS], xq[3*NPOS]);
      u1.z = cvtpk_u32(xq[4*NPOS], 0.f);
    }
    *(uint4*)&Act0[(sn*512 + col*16 + n16) << 3] = u0;
    *(uint4*)&Act1[(sn*512 + col*16 + n16) << 3] = u1;
  }
  preload_w<4,32>(wr, w1b, 0, 0, wave, lane);     // W1 (K=32 padded) -> slot 0
  __syncthreads();                                // (1) x-frags ready

  mfma_WA<1>(wr, w1b, Act0, Act1, b1, c0, c1, wave, lane);   // layer 1
  __syncthreads();                                // (2) x-frag reads done
  preload_w<4,256>(wr, w2b, 0, 0, wave, lane);    // W2 head behind epilogue
  preload_w<4,256>(wr, w2b, 1, 1, wave, lane);
  epilogue_relu(c0, Act0, wave, lane);
  epilogue_relu(c1, Act1, wave, lane);
  __syncthreads();                                // (3) Act = h1

  mfma_WA<8>(wr, w2b, Act0, Act1, b2, c0, c1, wave, lane);   // layer 2
  __syncthreads();                                // (4) h1 reads done
  preload_w<4,256>(wr, w3b, 0, 0, wave, lane);    // W3 head behind epilogue
  preload_w<4,256>(wr, w3b, 1, 1, wave, lane);
  epilogue_relu(c0, Act0, wave, lane);
  epilogue_relu(c1, Act1, wave, lane);
  __syncthreads();                                // (5) Act = h2

  mfma_WA<8>(wr, w3b, Act0, Act1, b3, c0, c1, wave, lane);   // layer 3
  __syncthreads();                                // (6) h2 reads done
  preload_w<2,256>(wr, w4b, 0, 0, wave, lane);    // W4 head behind epilogue
  preload_w<2,256>(wr, w4b, 1, 1, wave, lane);
  epilogue_relu(c0, Act0, wave, lane);
  epilogue_relu(c1, Act1, wave, lane);
  __syncthreads();                                // (7) Act = h3

  mfma_L4(wr, w4b, Act0, Act1, b4, c0, c1, wave, lane);      // layer 4
  {
    const int m = lane & 15, quad = lane >> 4;
    const float* mk = mask + (size_t)b*NPOS + n0;
    #pragma unroll
    for (int sd=0;sd<2;sd++){
      const int d = wave*32 + sd*16 + m;
      ushort_t* rowp = h4 + ((size_t)b*CO + d)*NPOS + n0;
      #pragma unroll
      for (int sn=0;sn<4;sn++){
        float4 mr0 = *(const float4*)(mk + sn*16 + quad*4);
        float4 mr1 = *(const float4*)(mk + 64 + sn*16 + quad*4);
        unsigned q0 = cvtpk_u32(c0[sn][sd][0] * (1.0f/512.0f) * mr0.x,
                                c0[sn][sd][1] * (1.0f/512.0f) * mr0.y);
        unsigned q1 = cvtpk_u32(c0[sn][sd][2] * (1.0f/512.0f) * mr0.z,
                                c0[sn][sd][3] * (1.0f/512.0f) * mr0.w);
        *(uint2*)(rowp + sn*16 + quad*4) = make_uint2(q0, q1);
        unsigned p0 = cvtpk_u32(c1[sn][sd][0] * (1.0f/512.0f) * mr1.x,
                                c1[sn][sd][1] * (1.0f/512.0f) * mr1.y);
        unsigned p1 = cvtpk_u32(c1[sn][sd][2] * (1.0f/512.0f) * mr1.z,
                                c1[sn][sd][3] * (1.0f/512.0f) * mr1.w);
        *(uint2*)(rowp + 64 + sn*16 + quad*4) = make_uint2(p0, p1);
      }
    }
  }
}

// ---------------- sort + pool (+ size feature fold) ----------------
// Packed bitonic, TWO rows per wave (row0 low u16 / row1 high u16 of 8 regs).
// xor 1,2,8 via DPP (VALU pipe); 4,16,32 via __shfl_xor. Direction-flip trick
// makes every CE fixed-ascending. Wt weight loads hoisted above the sort so
// their L2 latency hides under ~2200 cyc of bitonic VALU.

static __device__ __forceinline__ void ce_up(unsigned &a, unsigned &b){
  unsigned mn = pk_min_u16(a,b), mx = pk_max_u16(a,b); a = mn; b = mx;
}
static __device__ __forceinline__ void ce_dn(unsigned &a, unsigned &b){
  unsigned mn = pk_min_u16(a,b), mx = pk_max_u16(a,b); a = mx; b = mn;
}
static __device__ __forceinline__ void clean8(unsigned (&v)[8]){   // j=4,2,1 ascending
  ce_up(v[0],v[4]); ce_up(v[1],v[5]); ce_up(v[2],v[6]); ce_up(v[3],v[7]);
  ce_up(v[0],v[2]); ce_up(v[1],v[3]); ce_up(v[4],v[6]); ce_up(v[5],v[7]);
  ce_up(v[0],v[1]); ce_up(v[2],v[3]); ce_up(v[4],v[5]); ce_up(v[6],v[7]);
}
static __device__ __forceinline__ void flip8(unsigned (&v)[8], unsigned f){
  #pragma unroll
  for (int i=0;i<8;i++) v[i] ^= f;
}
template<int CTRL>
static __device__ __forceinline__ void xr_dpp(unsigned (&v)[8], bool low){
  #pragma unroll
  for (int i=0;i<8;i++){
    unsigned p = mov_dpp_u32<CTRL>(v[i]);
    unsigned mn = pk_min_u16(v[i], p), mx = pk_max_u16(v[i], p);
    v[i] = low ? mn : mx;
  }
}
static __device__ __forceinline__ void xr_shfl(unsigned (&v)[8], int lm, bool low){
  #pragma unroll
  for (int i=0;i<8;i++){
    unsigned p = (unsigned)__shfl_xor((int)v[i], lm);
    unsigned mn = pk_min_u16(v[i], p), mx = pk_max_u16(v[i], p);
    v[i] = low ? mn : mx;
  }
}

__global__ void k_pool(const ushort_t* __restrict__ h4, const float* __restrict__ Wt,
                       const float* __restrict__ mask, float* __restrict__ out)
{
  const int lane = threadIdx.x & 63;
  const int wave = threadIdx.x >> 6;
  const size_t r0 = (size_t)blockIdx.x*8 + wave*2;   // rows r0, r0+1
  const int b0 = (int)(r0 >> 7), c0 = (int)(r0 & 127);
  const int b1_ = (int)((r0+1) >> 7), c1 = (int)((r0+1) & 127);

  uint4 ra = *(const uint4*)(h4 + r0*NPOS     + lane*8);
  uint4 rb = *(const uint4*)(h4 + (r0+1)*NPOS + lane*8);

  // Wt loads issued NOW — latency hidden under the sort below
  float w0[8], w1a[8];
  *(float4*)&w0[0]  = *(const float4*)(Wt + c0*512 + lane*8);
  *(float4*)&w0[4]  = *(const float4*)(Wt + c0*512 + lane*8 + 4);
  *(float4*)&w1a[0] = *(const float4*)(Wt + c1*512 + lane*8);
  *(float4*)&w1a[4] = *(const float4*)(Wt + c1*512 + lane*8 + 4);

  unsigned v[8];
  v[0] = (ra.x & 0xFFFFu) | (rb.x << 16);
  v[1] = (ra.x >> 16)     | (rb.x & 0xFFFF0000u);
  v[2] = (ra.y & 0xFFFFu) | (rb.y << 16);
  v[3] = (ra.y >> 16)     | (rb.y & 0xFFFF0000u);
  v[4] = (ra.z & 0xFFFFu) | (rb.z << 16);
  v[5] = (ra.z >> 16)     | (rb.z & 0xFFFF0000u);
  v[6] = (ra.w & 0xFFFFu) | (rb.w << 16);
  v[7] = (ra.w >> 16)     | (rb.w & 0xFFFF0000u);

  // bf16 -> sortable u16 key (both halves at once)
  #pragma unroll
  for (int i=0;i<8;i++){
    unsigned sb = (v[i] >> 15) & 0x00010001u;
    v[i] = v[i] ^ 0x80008000u ^ (sb * 0x7FFFu);
  }

  const bool lo1  = (lane & 1)  == 0;
  const bool lo2  = (lane & 2)  == 0;
  const bool lo4  = (lane & 4)  == 0;
  const bool lo8  = (lane & 8)  == 0;
  const bool lo16 = (lane & 16) == 0;
  const bool lo32 = (lane & 32) == 0;

  const unsigned F8   = (lane & 1)  ? 0xFFFFFFFFu : 0u;
  const unsigned F16  = (lane & 2)  ? 0xFFFFFFFFu : 0u;
  const unsigned F32  = (lane & 4)  ? 0xFFFFFFFFu : 0u;
  const unsigned F64  = (lane & 8)  ? 0xFFFFFFFFu : 0u;
  const unsigned F128 = (lane & 16) ? 0xFFFFFFFFu : 0u;
  const unsigned F256 = (lane & 32) ? 0xFFFFFFFFu : 0u;

  // k=2, k=4 presort (fixed directions)
  ce_up(v[0],v[1]); ce_dn(v[2],v[3]); ce_up(v[4],v[5]); ce_dn(v[6],v[7]);
  ce_up(v[0],v[2]); ce_up(v[1],v[3]); ce_dn(v[4],v[6]); ce_dn(v[5],v[7]);
  ce_up(v[0],v[1]); ce_up(v[2],v[3]); ce_dn(v[4],v[5]); ce_dn(v[6],v[7]);

  flip8(v, F8);                                   // k=8 (in-lane only)
  clean8(v);
  flip8(v, F8 ^ F16);                             // k=16
  xr_dpp<0xB1>(v, lo1);
  clean8(v);
  flip8(v, F16 ^ F32);                            // k=32
  xr_dpp<0x4E>(v, lo2); xr_dpp<0xB1>(v, lo1);
  clean8(v);
  flip8(v, F32 ^ F64);                            // k=64
  xr_shfl(v, 4, lo4); xr_dpp<0x4E>(v, lo2); xr_dpp<0xB1>(v, lo1);
  clean8(v);
  flip8(v, F64 ^ F128);                           // k=128
  xr_dpp<0x128>(v, lo8); xr_shfl(v, 4, lo4); xr_dpp<0x4E>(v, lo2); xr_dpp<0xB1>(v, lo1);
  clean8(v);
  flip8(v, F128 ^ F256);                          // k=256
  xr_shfl(v, 16, lo16); xr_dpp<0x128>(v, lo8); xr_shfl(v, 4, lo4);
  xr_dpp<0x4E>(v, lo2); xr_dpp<0xB1>(v, lo1);
  clean8(v);
  flip8(v, F256);                                 // k=512 runs unflipped
  xr_shfl(v, 32, lo32); xr_shfl(v, 16, lo16); xr_dpp<0x128>(v, lo8);
  xr_shfl(v, 4, lo4); xr_dpp<0x4E>(v, lo2); xr_dpp<0xB1>(v, lo1);
  clean8(v);

  // key -> bf16 bits (both halves)
  #pragma unroll
  for (int i=0;i<8;i++){
    unsigned sb = ((~v[i]) >> 15) & 0x00010001u;
    v[i] = v[i] ^ 0x80008000u ^ (sb * 0x7FFFu);
  }

  float s0 = 0.f, s1 = 0.f;
  #pragma unroll
  for (int i=0;i<8;i++){
    union {unsigned u; float f;} lo, hi;
    lo.u = v[i] << 16;
    hi.u = v[i] & 0xFFFF0000u;
    s0 = fmaf(lo.f, w0[i],  s0);
    s1 = fmaf(hi.f, w1a[i], s1);
  }
  s0 = fadd_dpp<0xB1>(s0);  s1 = fadd_dpp<0xB1>(s1);
  s0 = fadd_dpp<0x4E>(s0);  s1 = fadd_dpp<0x4E>(s1);
  s0 = fadd_dpp<0x128>(s0); s1 = fadd_dpp<0x128>(s1);
  s0 += __shfl_xor(s0, 4);  s1 += __shfl_xor(s1, 4);
  s0 += __shfl_xor(s0, 16); s1 += __shfl_xor(s1, 16);
  s0 += __shfl_xor(s0, 32); s1 += __shfl_xor(s1, 32);

  if (lane == 0){
    out[b0*129 + c0]  = s0;
    out[b1_*129 + c1] = s1;
  }

  // folded size feature: blocks 0..1023, wave 0 compute out[b,128]
  if (blockIdx.x < 1024 && wave == 0){
    const int b = blockIdx.x;
    float s = 0.f;
    #pragma unroll
    for (int i=0;i<2;i++){
      float4 mv = *(const float4*)(mask + (size_t)b*NPOS + lane*8 + i*4);
      s += mv.x + mv.y + mv.z + mv.w;
    }
    s = fadd_dpp<0xB1>(s); s = fadd_dpp<0x4E>(s); s = fadd_dpp<0x128>(s);
    s += __shfl_xor(s, 4); s += __shfl_xor(s, 16); s += __shfl_xor(s, 32);
    if (lane == 0) out[b*129 + 128] = s * (1.0f/128.0f);  // mean*4 = sum/512*4
  }
}

extern "C" void kernel_launch(void* const* d_in, const int* in_sizes, int n_in,
                              void* d_out, int out_size, void* d_ws, size_t ws_size,
                              hipStream_t stream){
  const float* x    = (const float*)d_in[0];
  const float* mask = (const float*)d_in[1];
  const float* w1   = (const float*)d_in[2];
  const float* b1   = (const float*)d_in[3];
  const float* w2   = (const float*)d_in[4];
  const float* b2   = (const float*)d_in[5];
  const float* w3   = (const float*)d_in[6];
  const float* b3   = (const float*)d_in[7];
  const float* w4   = (const float*)d_in[8];
  const float* b4   = (const float*)d_in[9];
  const float* pw   = (const float*)d_in[10];
  float* out = (float*)d_out;

  // ws: h4 bf16 (1024*128*512 = 128MB) | w2b | w3b | w4b | w1b | Wt (f32 128x512)
  ushort_t* h4  = (ushort_t*)d_ws;
  ushort_t* w2b = h4 + (size_t)1024*CO*NPOS;
  ushort_t* w3b = w2b + 65536;
  ushort_t* w4b = w3b + 65536;
  ushort_t* w1b = w4b + 32768;
  float*    Wt  = (float*)(w1b + 8192);

  k_prep <<<928,   256, 0, stream>>>(w1, w2, w3, w4, pw, w2b, Wt);
  k_fused<<<4096,  256, 0, stream>>>(x, mask, w1b, b1, w2b, b2, w3b, b3, w4b, b4, h4);
  k_pool <<<16384, 256, 0, stream>>>(h4, Wt, mask, out);
}

// Round 12
// 383.356 us; speedup vs baseline: 1.0253x; 1.0047x over previous
//
#include <hip/hip_runtime.h>
#include <hip/hip_bf16.h>

typedef __bf16 bf16x8 __attribute__((ext_vector_type(8)));
typedef float f32x4 __attribute__((ext_vector_type(4)));
typedef unsigned u32x4v __attribute__((ext_vector_type(4)));
typedef unsigned u32x2v __attribute__((ext_vector_type(2)));
typedef unsigned short ushort_t;

#define NPOS 512
#define CIN  5
#define CO   128

static __device__ __forceinline__ unsigned short f2bf(float f){
  union { __hip_bfloat16 h; unsigned short u; } cv;
  cv.h = __float2bfloat16(f);
  return cv.u;
}

// packed f32->bf16x2 (v_cvt_pk_bf16_f32 on gfx950) — RNE, 1 op per 2 values
static __device__ __forceinline__ unsigned cvtpk_u32(float a, float b){
  union { __hip_bfloat162 h2; unsigned u; } cv;
  cv.h2 = __float22bfloat162_rn(make_float2(a, b));
  return cv.u;
}

// packed u16 min/max (VOP3P) — one op handles two independent sort rows
static __device__ __forceinline__ unsigned pk_min_u16(unsigned a, unsigned b){
  unsigned d; asm("v_pk_min_u16 %0, %1, %2" : "=v"(d) : "v"(a), "v"(b)); return d;
}
static __device__ __forceinline__ unsigned pk_max_u16(unsigned a, unsigned b){
  unsigned d; asm("v_pk_max_u16 %0, %1, %2" : "=v"(d) : "v"(a), "v"(b)); return d;
}
// packed i16 max — relu on 2 packed bf16 (sign-correct; -0.0 -> +0.0)
static __device__ __forceinline__ unsigned pk_max_i16(unsigned a, unsigned b){
  unsigned d; asm("v_pk_max_i16 %0, %1, %2" : "=v"(d) : "v"(a), "v"(b)); return d;
}

// DPP cross-lane fetch (VALU pipe, no DS): 0xB1=xor1, 0x4E=xor2, 0x128=xor8
template<int CTRL>
static __device__ __forceinline__ unsigned mov_dpp_u32(unsigned v){
  return (unsigned)__builtin_amdgcn_mov_dpp((int)v, CTRL, 0xf, 0xf, true);
}
template<int CTRL>
static __device__ __forceinline__ float fadd_dpp(float s){
  union {float f; int i;} u; u.f = s;
  union {int i; float f;} q; q.i = __builtin_amdgcn_mov_dpp(u.i, CTRL, 0xf, 0xf, true);
  return s + q.f;
}

// ---------------- weight fp32 -> bf16 prep (+ fspool weight table) ----------------
// o = [w2b 65536 | w3b 65536 | w4b 32768 (PRE-SCALED by 1/512) | w1b 8192]
// Wt[c][i] (f32, 128x512) = pool weight at descending rank 511-i
// b4s[128] = b4/512 (so L4 epilogue only multiplies by mask)
__global__ void k_prep(const float* __restrict__ w1, const float* __restrict__ w2,
                       const float* __restrict__ w3, const float* __restrict__ w4,
                       const float* __restrict__ pw, const float* __restrict__ b4,
                       ushort_t* __restrict__ o, float* __restrict__ Wt,
                       float* __restrict__ b4s){
  int i = blockIdx.x*256 + threadIdx.x;
  if (i < 65536)        o[i] = f2bf(w2[i]);
  else if (i < 131072)  o[i] = f2bf(w3[i-65536]);
  else if (i < 163840)  o[i] = f2bf(w4[i-131072] * (1.0f/512.0f));  // exponent shift, exact
  else if (i < 172032){
    int j = i - 163840;                   // 0..8191
    int d = j >> 5, k = j & 31;
    o[i] = (k < CIN) ? f2bf(w1[d*CIN + k]) : (ushort_t)0;
  } else if (i < 237568){
    int j = i - 172032;                   // 0..65535
    int c = j >> 9, ii = j & 511;
    int rk = 511 - ii;
    float pos = (float)rk * (20.0f/511.0f);
    int idx = (int)pos; if (idx > 20) idx = 20;
    float frac = pos - (float)idx;
    int i2 = (idx+1 > 20) ? 20 : idx+1;
    float wl = pw[c*21 + idx], wr = pw[c*21 + i2];
    Wt[c*512 + ii] = wl + frac*(wr - wl);
  } else if (i < 237696){
    b4s[i-237568] = b4[i-237568] * (1.0f/512.0f);
  }
}

// ---------------- fused conv1..conv4 (all-MFMA, 2-tile W reuse) ----------------
// Block owns (batch b, 128-n pair of tiles). Two in-place 32 KB Act buffers,
// fragment-major chunks: chunk(n,c) = (n>>4)*512 + (c>>5)*64 + ((c>>3)&3)*16 + (n&15),
// j-slot = c&7. Act-read (nb,ks): chunk = nb*512 + ks*64 + lane (lane-seq b128).
// Layers 1-3: W as MFMA A-operand (C/D: lane=n, quad*4+reg = 4 consecutive d)
// -> b64 epilogue writes. Layer 4: Act as A (n-consecutive global store).
// Bias as ks=0 C operand. W preloads after the read barrier, behind epilogue
// VALU (R10's in-loop variant spilled). h4 stores are NON-TEMPORAL: h4 is
// write-once/read-once 128 MB — keep it from evicting L2-resident W.

template<int NSD, int KSTR>
static __device__ __forceinline__ void preload_w(bf16x8 (&wr)[3][4],
    const ushort_t* __restrict__ Wb, int slot, int ks, int wave, int lane){
  const int m = lane & 15, quad = lane >> 4;
  const int d0 = wave * (NSD*16);
  #pragma unroll
  for (int sd=0; sd<NSD; sd++)
    wr[slot][sd] = *(const bf16x8*)(Wb + (d0 + sd*16 + m)*KSTR + ks*32 + quad*8);
}

// layers 1-3: W as A-operand, Act as B-operand. acc[nb][db]:
//   n = nb*16 + (lane&15), d = wave*64 + db*16 + quad*4 + rg
template<int NKS>
static __device__ __forceinline__ void mfma_WA(bf16x8 (&wr)[3][4],
    const ushort_t* __restrict__ Wb,
    const ushort_t* __restrict__ A0, const ushort_t* __restrict__ A1,
    const float* __restrict__ bias,
    f32x4 (&c0)[4][4], f32x4 (&c1)[4][4], int wave, int lane){
  const int quad = lane >> 4;
  f32x4 bvv[4];
  #pragma unroll
  for (int db=0; db<4; db++){
    float4 b4v = *(const float4*)(bias + wave*64 + db*16 + quad*4);
    bvv[db] = (f32x4){b4v.x, b4v.y, b4v.z, b4v.w};
  }
  #pragma unroll
  for (int ks=0; ks<NKS; ks++){
    if (ks+2 < NKS) preload_w<4,256>(wr, Wb, (ks+2)%3, ks+2, wave, lane);
    bf16x8 a0[4], a1[4];
    #pragma unroll
    for (int nb=0; nb<4; nb++){
      a0[nb] = *(const bf16x8*)(A0 + ((nb*512 + ks*64 + lane) << 3));
      a1[nb] = *(const bf16x8*)(A1 + ((nb*512 + ks*64 + lane) << 3));
    }
    #pragma unroll
    for (int db=0; db<4; db++){
      #pragma unroll
      for (int nb=0; nb<4; nb++){
        if (ks == 0){
          c0[nb][db] = __builtin_amdgcn_mfma_f32_16x16x32_bf16(wr[0][db], a0[nb], bvv[db], 0,0,0);
          c1[nb][db] = __builtin_amdgcn_mfma_f32_16x16x32_bf16(wr[0][db], a1[nb], bvv[db], 0,0,0);
        } else {
          c0[nb][db] = __builtin_amdgcn_mfma_f32_16x16x32_bf16(wr[ks%3][db], a0[nb], c0[nb][db], 0,0,0);
          c1[nb][db] = __builtin_amdgcn_mfma_f32_16x16x32_bf16(wr[ks%3][db], a1[nb], c1[nb][db], 0,0,0);
        }
      }
    }
  }
}

// layer 4: Act as A-operand. acc[sn][sd]:
//   n = sn*16 + quad*4 + rg, d = wave*32 + sd*16 + (lane&15)
static __device__ __forceinline__ void mfma_L4(bf16x8 (&wr)[3][4],
    const ushort_t* __restrict__ Wb,
    const ushort_t* __restrict__ A0, const ushort_t* __restrict__ A1,
    const float* __restrict__ bias,
    f32x4 (&c0)[4][4], f32x4 (&c1)[4][4], int wave, int lane){
  const int m = lane & 15;
  f32x4 bvv[2];
  #pragma unroll
  for (int sd=0; sd<2; sd++){
    float bv = bias[wave*32 + sd*16 + m];
    bvv[sd] = (f32x4){bv,bv,bv,bv};
  }
  #pragma unroll
  for (int ks=0; ks<8; ks++){
    if (ks+2 < 8) preload_w<2,256>(wr, Wb, (ks+2)%3, ks+2, wave, lane);
    bf16x8 a0[4], a1[4];
    #pragma unroll
    for (int sn=0; sn<4; sn++){
      a0[sn] = *(const bf16x8*)(A0 + ((sn*512 + ks*64 + lane) << 3));
      a1[sn] = *(const bf16x8*)(A1 + ((sn*512 + ks*64 + lane) << 3));
    }
    #pragma unroll
    for (int sd=0; sd<2; sd++){
      #pragma unroll
      for (int sn=0; sn<4; sn++){
        if (ks == 0){
          c0[sn][sd] = __builtin_amdgcn_mfma_f32_16x16x32_bf16(a0[sn], wr[0][sd], bvv[sd], 0,0,0);
          c1[sn][sd] = __builtin_amdgcn_mfma_f32_16x16x32_bf16(a1[sn], wr[0][sd], bvv[sd], 0,0,0);
        } else {
          c0[sn][sd] = __builtin_amdgcn_mfma_f32_16x16x32_bf16(a0[sn], wr[ks%3][sd], c0[sn][sd], 0,0,0);
          c1[sn][sd] = __builtin_amdgcn_mfma_f32_16x16x32_bf16(a1[sn], wr[ks%3][sd], c1[sn][sd], 0,0,0);
        }
      }
    }
  }
}

// layers 1-3 epilogue: +relu, ONE b64 write per acc tile (4 consecutive c)
static __device__ __forceinline__ void epilogue_relu(const f32x4 (&c)[4][4],
    ushort_t* __restrict__ dst, int wave, int lane){
  const int m = lane & 15, quad = lane >> 4;
  #pragma unroll
  for (int db=0; db<4; db++){
    int cb    = wave*64 + db*16 + quad*4;
    int colpt = (cb>>5)*64 + ((cb>>3)&3)*16;     // chunk col part
    int half  = (quad & 1) ? 4 : 0;              // 8B half within 16B chunk
    #pragma unroll
    for (int nb=0; nb<4; nb++){
      unsigned u01 = pk_max_i16(cvtpk_u32(c[nb][db][0], c[nb][db][1]), 0u);
      unsigned u23 = pk_max_i16(cvtpk_u32(c[nb][db][2], c[nb][db][3]), 0u);
      int chunk = nb*512 + colpt + m;
      *(uint2*)&dst[(chunk << 3) + half] = make_uint2(u01, u23);
    }
  }
}

__global__ __launch_bounds__(256,2) void k_fused(
  const float* __restrict__ x, const float* __restrict__ mask,
  const ushort_t* __restrict__ w1b, const float* __restrict__ b1,
  const ushort_t* __restrict__ w2b, const float* __restrict__ b2,
  const ushort_t* __restrict__ w3b, const float* __restrict__ b3,
  const ushort_t* __restrict__ w4b, const float* __restrict__ b4s,
  ushort_t* __restrict__ h4)
{
  __shared__ __align__(16) ushort_t Act0[64*256];   // 32 KB each, in-place
  __shared__ __align__(16) ushort_t Act1[64*256];
  const int t    = threadIdx.x;
  const int bid  = blockIdx.x;
  const int b    = bid >> 2;
  const int n0   = (bid & 3) << 7;       // tiles at n0 and n0+64
  const int wave = t >> 6, lane = t & 63;

  bf16x8 wr[3][4];
  f32x4  c0[4][4], c1[4][4];

  // Build layer-1 fragments (ks=0 chunks) straight from global x, both tiles.
  {
    const int sn = t >> 6, col = (t >> 4) & 3, n16 = t & 15;
    uint4 u0 = make_uint4(0u,0u,0u,0u), u1 = u0;
    if (col == 0){
      const float* xp = x + (size_t)b*CIN*NPOS + n0 + sn*16 + n16;
      u0.x = cvtpk_u32(xp[0],      xp[NPOS]);
      u0.y = cvtpk_u32(xp[2*NPOS], xp[3*NPOS]);
      u0.z = cvtpk_u32(xp[4*NPOS], 0.f);
      const float* xq = xp + 64;
      u1.x = cvtpk_u32(xq[0],      xq[NPOS]);
      u1.y = cvtpk_u32(xq[2*NPOS], xq[3*NPOS]);
      u1.z = cvtpk_u32(xq[4*NPOS], 0.f);
    }
    *(uint4*)&Act0[(sn*512 + col*16 + n16) << 3] = u0;
    *(uint4*)&Act1[(sn*512 + col*16 + n16) << 3] = u1;
  }
  preload_w<4,32>(wr, w1b, 0, 0, wave, lane);     // W1 (K=32 padded) -> slot 0
  __syncthreads();                                // (1) x-frags ready

  mfma_WA<1>(wr, w1b, Act0, Act1, b1, c0, c1, wave, lane);   // layer 1
  __syncthreads();                                // (2) x-frag reads done
  preload_w<4,256>(wr, w2b, 0, 0, wave, lane);    // W2 head behind epilogue
  preload_w<4,256>(wr, w2b, 1, 1, wave, lane);
  epilogue_relu(c0, Act0, wave, lane);
  epilogue_relu(c1, Act1, wave, lane);
  __syncthreads();                                // (3) Act = h1

  mfma_WA<8>(wr, w2b, Act0, Act1, b2, c0, c1, wave, lane);   // layer 2
  __syncthreads();                                // (4) h1 reads done
  preload_w<4,256>(wr, w3b, 0, 0, wave, lane);    // W3 head behind epilogue
  preload_w<4,256>(wr, w3b, 1, 1, wave, lane);
  epilogue_relu(c0, Act0, wave, lane);
  epilogue_relu(c1, Act1, wave, lane);
  __syncthreads();                                // (5) Act = h2

  mfma_WA<8>(wr, w3b, Act0, Act1, b3, c0, c1, wave, lane);   // layer 3
  __syncthreads();                                // (6) h2 reads done
  preload_w<2,256>(wr, w4b, 0, 0, wave, lane);    // W4 head behind epilogue
  preload_w<2,256>(wr, w4b, 1, 1, wave, lane);
  epilogue_relu(c0, Act0, wave, lane);
  epilogue_relu(c1, Act1, wave, lane);
  __syncthreads();                                // (7) Act = h3

  mfma_L4(wr, w4b, Act0, Act1, b4s, c0, c1, wave, lane);     // layer 4 (pre-scaled)
  {
    const int m = lane & 15, quad = lane >> 4;
    const float* mk = mask + (size_t)b*NPOS + n0;
    #pragma unroll
    for (int sd=0;sd<2;sd++){
      const int d = wave*32 + sd*16 + m;
      ushort_t* rowp = h4 + ((size_t)b*CO + d)*NPOS + n0;
      #pragma unroll
      for (int sn=0;sn<4;sn++){
        float4 mr0 = *(const float4*)(mk + sn*16 + quad*4);
        float4 mr1 = *(const float4*)(mk + 64 + sn*16 + quad*4);
        u32x2v q, p;
        q[0] = cvtpk_u32(c0[sn][sd][0] * mr0.x, c0[sn][sd][1] * mr0.y);
        q[1] = cvtpk_u32(c0[sn][sd][2] * mr0.z, c0[sn][sd][3] * mr0.w);
        __builtin_nontemporal_store(q, (u32x2v*)(rowp + sn*16 + quad*4));
        p[0] = cvtpk_u32(c1[sn][sd][0] * mr1.x, c1[sn][sd][1] * mr1.y);
        p[1] = cvtpk_u32(c1[sn][sd][2] * mr1.z, c1[sn][sd][3] * mr1.w);
        __builtin_nontemporal_store(p, (u32x2v*)(rowp + 64 + sn*16 + quad*4));
      }
    }
  }
}

// ---------------- sort + pool (+ size feature fold) ----------------
// Packed bitonic, TWO rows per wave (row0 low u16 / row1 high u16 of 8 regs).
// xor 1,2,8 via DPP (VALU pipe); 4,16,32 via __shfl_xor. Direction-flip trick
// makes every CE fixed-ascending. Wt loads AFTER the sort (R10's hoist held
// 16 VGPRs live through ~2000 cyc — cost more than the latency it hid).
// h4 reads non-temporal (read-once, keep out of L2).

static __device__ __forceinline__ void ce_up(unsigned &a, unsigned &b){
  unsigned mn = pk_min_u16(a,b), mx = pk_max_u16(a,b); a = mn; b = mx;
}
static __device__ __forceinline__ void ce_dn(unsigned &a, unsigned &b){
  unsigned mn = pk_min_u16(a,b), mx = pk_max_u16(a,b); a = mx; b = mn;
}
static __device__ __forceinline__ void clean8(unsigned (&v)[8]){   // j=4,2,1 ascending
  ce_up(v[0],v[4]); ce_up(v[1],v[5]); ce_up(v[2],v[6]); ce_up(v[3],v[7]);
  ce_up(v[0],v[2]); ce_up(v[1],v[3]); ce_up(v[4],v[6]); ce_up(v[5],v[7]);
  ce_up(v[0],v[1]); ce_up(v[2],v[3]); ce_up(v[4],v[5]); ce_up(v[6],v[7]);
}
static __device__ __forceinline__ void flip8(unsigned (&v)[8], unsigned f){
  #pragma unroll
  for (int i=0;i<8;i++) v[i] ^= f;
}
template<int CTRL>
static __device__ __forceinline__ void xr_dpp(unsigned (&v)[8], bool low){
  #pragma unroll
  for (int i=0;i<8;i++){
    unsigned p = mov_dpp_u32<CTRL>(v[i]);
    unsigned mn = pk_min_u16(v[i], p), mx = pk_max_u16(v[i], p);
    v[i] = low ? mn : mx;
  }
}
static __device__ __forceinline__ void xr_shfl(unsigned (&v)[8], int lm, bool low){
  #pragma unroll
  for (int i=0;i<8;i++){
    unsigned p = (unsigned)__shfl_xor((int)v[i], lm);
    unsigned mn = pk_min_u16(v[i], p), mx = pk_max_u16(v[i], p);
    v[i] = low ? mn : mx;
  }
}

__global__ void k_pool(const ushort_t* __restrict__ h4, const float* __restrict__ Wt,
                       const float* __restrict__ mask, float* __restrict__ out)
{
  const int lane = threadIdx.x & 63;
  const int wave = threadIdx.x >> 6;
  const size_t r0 = (size_t)blockIdx.x*8 + wave*2;   // rows r0, r0+1
  const int b0 = (int)(r0 >> 7), c0 = (int)(r0 & 127);
  const int b1_ = (int)((r0+1) >> 7), c1 = (int)((r0+1) & 127);

  u32x4v ra = __builtin_nontemporal_load((const u32x4v*)(h4 + r0*NPOS     + lane*8));
  u32x4v rb = __builtin_nontemporal_load((const u32x4v*)(h4 + (r0+1)*NPOS + lane*8));

  unsigned v[8];
  v[0] = (ra[0] & 0xFFFFu) | (rb[0] << 16);
  v[1] = (ra[0] >> 16)     | (rb[0] & 0xFFFF0000u);
  v[2] = (ra[1] & 0xFFFFu) | (rb[1] << 16);
  v[3] = (ra[1] >> 16)     | (rb[1] & 0xFFFF0000u);
  v[4] = (ra[2] & 0xFFFFu) | (rb[2] << 16);
  v[5] = (ra[2] >> 16)     | (rb[2] & 0xFFFF0000u);
  v[6] = (ra[3] & 0xFFFFu) | (rb[3] << 16);
  v[7] = (ra[3] >> 16)     | (rb[3] & 0xFFFF0000u);

  // bf16 -> sortable u16 key (both halves at once)
  #pragma unroll
  for (int i=0;i<8;i++){
    unsigned sb = (v[i] >> 15) & 0x00010001u;
    v[i] = v[i] ^ 0x80008000u ^ (sb * 0x7FFFu);
  }

  const bool lo1  = (lane & 1)  == 0;
  const bool lo2  = (lane & 2)  == 0;
  const bool lo4  = (lane & 4)  == 0;
  const bool lo8  = (lane & 8)  == 0;
  const bool lo16 = (lane & 16) == 0;
  const bool lo32 = (lane & 32) == 0;

  const unsigned F8   = (lane & 1)  ? 0xFFFFFFFFu : 0u;
  const unsigned F16  = (lane & 2)  ? 0xFFFFFFFFu : 0u;
  const unsigned F32  = (lane & 4)  ? 0xFFFFFFFFu : 0u;
  const unsigned F64  = (lane & 8)  ? 0xFFFFFFFFu : 0u;
  const unsigned F128 = (lane & 16) ? 0xFFFFFFFFu : 0u;
  const unsigned F256 = (lane & 32) ? 0xFFFFFFFFu : 0u;

  // k=2, k=4 presort (fixed directions)
  ce_up(v[0],v[1]); ce_dn(v[2],v[3]); ce_up(v[4],v[5]); ce_dn(v[6],v[7]);
  ce_up(v[0],v[2]); ce_up(v[1],v[3]); ce_dn(v[4],v[6]); ce_dn(v[5],v[7]);
  ce_up(v[0],v[1]); ce_up(v[2],v[3]); ce_dn(v[4],v[5]); ce_dn(v[6],v[7]);

  flip8(v, F8);                                   // k=8 (in-lane only)
  clean8(v);
  flip8(v, F8 ^ F16);                             // k=16
  xr_dpp<0xB1>(v, lo1);
  clean8(v);
  flip8(v, F16 ^ F32);                            // k=32
  xr_dpp<0x4E>(v, lo2); xr_dpp<0xB1>(v, lo1);
  clean8(v);
  flip8(v, F32 ^ F64);                            // k=64
  xr_shfl(v, 4, lo4); xr_dpp<0x4E>(v, lo2); xr_dpp<0xB1>(v, lo1);
  clean8(v);
  flip8(v, F64 ^ F128);                           // k=128
  xr_dpp<0x128>(v, lo8); xr_shfl(v, 4, lo4); xr_dpp<0x4E>(v, lo2); xr_dpp<0xB1>(v, lo1);
  clean8(v);
  flip8(v, F128 ^ F256);                          // k=256
  xr_shfl(v, 16, lo16); xr_dpp<0x128>(v, lo8); xr_shfl(v, 4, lo4);
  xr_dpp<0x4E>(v, lo2); xr_dpp<0xB1>(v, lo1);
  clean8(v);
  flip8(v, F256);                                 // k=512 runs unflipped
  xr_shfl(v, 32, lo32); xr_shfl(v, 16, lo16); xr_dpp<0x128>(v, lo8);
  xr_shfl(v, 4, lo4); xr_dpp<0x4E>(v, lo2); xr_dpp<0xB1>(v, lo1);
  clean8(v);

  // key -> bf16 bits (both halves)
  #pragma unroll
  for (int i=0;i<8;i++){
    unsigned sb = ((~v[i]) >> 15) & 0x00010001u;
    v[i] = v[i] ^ 0x80008000u ^ (sb * 0x7FFFu);
  }

  // dot with precomputed weights (ascending position i = lane*8 + reg)
  float w0[8], w1a[8];
  *(float4*)&w0[0]  = *(const float4*)(Wt + c0*512 + lane*8);
  *(float4*)&w0[4]  = *(const float4*)(Wt + c0*512 + lane*8 + 4);
  *(float4*)&w1a[0] = *(const float4*)(Wt + c1*512 + lane*8);
  *(float4*)&w1a[4] = *(const float4*)(Wt + c1*512 + lane*8 + 4);

  float s0 = 0.f, s1 = 0.f;
  #pragma unroll
  for (int i=0;i<8;i++){
    union {unsigned u; float f;} lo, hi;
    lo.u = v[i] << 16;
    hi.u = v[i] & 0xFFFF0000u;
    s0 = fmaf(lo.f, w0[i],  s0);
    s1 = fmaf(hi.f, w1a[i], s1);
  }
  s0 = fadd_dpp<0xB1>(s0);  s1 = fadd_dpp<0xB1>(s1);
  s0 = fadd_dpp<0x4E>(s0);  s1 = fadd_dpp<0x4E>(s1);
  s0 = fadd_dpp<0x128>(s0); s1 = fadd_dpp<0x128>(s1);
  s0 += __shfl_xor(s0, 4);  s1 += __shfl_xor(s1, 4);
  s0 += __shfl_xor(s0, 16); s1 += __shfl_xor(s1, 16);
  s0 += __shfl_xor(s0, 32); s1 += __shfl_xor(s1, 32);

  if (lane == 0){
    out[b0*129 + c0]  = s0;
    out[b1_*129 + c1] = s1;
  }

  // folded size feature: blocks 0..1023, wave 0 compute out[b,128]
  if (blockIdx.x < 1024 && wave == 0){
    const int b = blockIdx.x;
    float s = 0.f;
    #pragma unroll
    for (int i=0;i<2;i++){
      float4 mv = *(const float4*)(mask + (size_t)b*NPOS + lane*8 + i*4);
      s += mv.x + mv.y + mv.z + mv.w;
    }
    s = fadd_dpp<0xB1>(s); s = fadd_dpp<0x4E>(s); s = fadd_dpp<0x128>(s);
    s += __shfl_xor(s, 4); s += __shfl_xor(s, 16); s += __shfl_xor(s, 32);
    if (lane == 0) out[b*129 + 128] = s * (1.0f/128.0f);  // mean*4 = sum/512*4
  }
}

extern "C" void kernel_launch(void* const* d_in, const int* in_sizes, int n_in,
                              void* d_out, int out_size, void* d_ws, size_t ws_size,
                              hipStream_t stream){
  const float* x    = (const float*)d_in[0];
  const float* mask = (const float*)d_in[1];
  const float* w1   = (const float*)d_in[2];
  const float* b1   = (const float*)d_in[3];
  const float* w2   = (const float*)d_in[4];
  const float* b2   = (const float*)d_in[5];
  const float* w3   = (const float*)d_in[6];
  const float* b3   = (const float*)d_in[7];
  const float* w4   = (const float*)d_in[8];
  const float* b4   = (const float*)d_in[9];
  const float* pw   = (const float*)d_in[10];
  float* out = (float*)d_out;

  // ws: h4 bf16 (128MB) | w2b | w3b | w4b | w1b | Wt (f32 128x512) | b4s (f32 128)
  ushort_t* h4  = (ushort_t*)d_ws;
  ushort_t* w2b = h4 + (size_t)1024*CO*NPOS;
  ushort_t* w3b = w2b + 65536;
  ushort_t* w4b = w3b + 65536;
  ushort_t* w1b = w4b + 32768;
  float*    Wt  = (float*)(w1b + 8192);
  float*    b4s = Wt + 65536;

  k_prep <<<929,   256, 0, stream>>>(w1, w2, w3, w4, pw, b4, w2b, Wt, b4s);
  k_fused<<<4096,  256, 0, stream>>>(x, mask, w1b, b1, w2b, b2, w3b, b3, w4b, b4s, h4);
  k_pool <<<16384, 256, 0, stream>>>(h4, Wt, mask, out);
}